// Round 1
// 1485.107 us; speedup vs baseline: 1.2029x; 1.2029x over previous
//
#include <hip/hip_runtime.h>
#include <stdint.h>

#define N_NODES 1000000
#define HID 256
#define HH  128
#define NG  1024
#define TILE 32
#define CHUNK 1984                      // 62 tiles of 32 nodes
#define NBLOCKS ((N_NODES + CHUNK - 1) / CHUNK)   // 505

typedef short short8v __attribute__((ext_vector_type(8)));
typedef float f32x4 __attribute__((ext_vector_type(4)));

#define GLOBAL_AS __attribute__((address_space(1)))
#define LDS_AS    __attribute__((address_space(3)))

// f32 -> bf16 (RNE), inputs finite
__device__ __forceinline__ unsigned short f2bf(float f){
  unsigned u = __float_as_uint(f);
  u += 0x7FFFu + ((u >> 16) & 1u);
  return (unsigned short)(u >> 16);
}

__device__ __forceinline__ float fast_tanh(float v){
  float e = __expf(2.f * v);
  return 1.f - 2.f / (e + 1.f);
}

// --- transform w1 [256][128] f32 -> bf16 B-fragment layout in ws ---
// layout: [nt(8)][ks(8)][lane(64)][i(8)]  where B[k][n]: n = nt*16 + (lane&15),
// k = ks*32 + (lane>>4)*8 + i
__global__ void k_prep(const float* __restrict__ w1, unsigned short* __restrict__ w1f){
  int s = blockIdx.x * blockDim.x + threadIdx.x;
  if (s >= 4096) return;
  int nt = s >> 9, rem = s & 511, ks = rem >> 6, lane = rem & 63;
  int q = lane >> 4, c = lane & 15;
  union { unsigned short u[8]; uint4 v; } tmp;
  for (int i = 0; i < 8; ++i){
    int k = ks * 32 + q * 8 + i;
    int n = nt * 16 + c;
    tmp.u[i] = f2bf(w1[k * HH + n]);
  }
  *(uint4*)(w1f + (size_t)s * 8) = tmp.v;
}

// stage one 32-node x-tile (32 KB) into LDS via global_load_lds.
// LDS layout is linear; the swizzle (16B-chunk index ^ (row&15)) is applied by
// permuting the per-lane GLOBAL source address (both-sides-or-neither rule).
__device__ __forceinline__ void stage_tile(const float* __restrict__ x, long node0,
                                           float* lds_tile, int wave, int lane){
  #pragma unroll
  for (int rr = 0; rr < 8; ++rr){
    int r = wave * 8 + rr;
    const float* gp = x + (size_t)(node0 + r) * HID + ((lane ^ (r & 15)) << 2);
    __builtin_amdgcn_global_load_lds(
        (const GLOBAL_AS unsigned int*)gp,
        (LDS_AS unsigned int*)(lds_tile + r * HID),
        16, 0, 0);
  }
}

// --- fused: score (MFMA) + exp + denom atomics + unnormalized pooling.
// Each block owns a contiguous CHUNK of nodes; x is read from HBM exactly once.
__global__ __launch_bounds__(256, 2) void k_fused(
    const float* __restrict__ x, const unsigned short* __restrict__ w1f,
    const float* __restrict__ b1, const float* __restrict__ w2,
    const float* __restrict__ b2, const int* __restrict__ batch,
    float* __restrict__ denom, float* __restrict__ out)
{
  __shared__ __align__(16) float xs[2][TILE * HID];   // 2 x 32 KB double buffer
  __shared__ int   b_all[CHUNK];                      // 7936 B
  __shared__ float partial_s[4][TILE];                // cross-wave score partials
  __shared__ float e_s[TILE];

  const int tid = threadIdx.x;
  const long base = (long)blockIdx.x * CHUNK;
  if (base >= N_NODES) return;
  long rem = (long)N_NODES - base;
  const int nvalid = (rem < CHUNK) ? (int)rem : CHUNK;   // always a multiple of 32
  const int ntiles = nvalid / TILE;

  const int wave = tid >> 6, lane = tid & 63;
  const int q = lane >> 4, col = lane & 15;

  // batch chunk -> LDS (synced by the loop-top barrier before first use)
  for (int i = tid; i < nvalid; i += 256) b_all[i] = batch[base + i];

  // this wave's 2 nt values of w1, kept in registers (64 VGPRs)
  short8v wf0[8], wf1[8];
  #pragma unroll
  for (int ks = 0; ks < 8; ++ks){
    int nt0 = wave * 2;
    wf0[ks] = *(const short8v*)(w1f + (((size_t)nt0 * 8 + ks) * 64 + lane) * 8);
    wf1[ks] = *(const short8v*)(w1f + ((((size_t)nt0 + 1) * 8 + ks) * 64 + lane) * 8);
  }
  float b1v0 = b1[wave * 32 + col],      w2v0 = w2[wave * 32 + col];
  float b1v1 = b1[wave * 32 + 16 + col], w2v1 = w2[wave * 32 + 16 + col];
  const float b2v = b2[0];

  // prologue: stage tile 0
  stage_tile(x, base, &xs[0][0], wave, lane);

  float accp = 0.f;          // pooling accumulator: thread owns column tid
  int curg = batch[base];    // uniform across block

  for (int t = 0; t < ntiles; ++t){
    const int par = t & 1;
    __syncthreads();   // B0: drains stage(t) (implicit vmcnt(0)), syncs b_all/pool(t-1)

    if (t + 1 < ntiles)
      stage_tile(x, base + (long)(t + 1) * TILE, &xs[par ^ 1][0], wave, lane);

    const float* xb = &xs[par][0];

    // ---- score phase: 2 row-groups x 8 k-steps x 2 nt per wave
    f32x4 acc00 = {0.f,0.f,0.f,0.f}, acc01 = {0.f,0.f,0.f,0.f};
    f32x4 acc10 = {0.f,0.f,0.f,0.f}, acc11 = {0.f,0.f,0.f,0.f};
    #pragma unroll
    for (int ks = 0; ks < 8; ++ks){
      const int k16 = ks * 8 + q * 2;
      #pragma unroll
      for (int rg = 0; rg < 2; ++rg){
        const int R  = rg * 16 + col;
        const int sw = R & 15;
        f32x4 xa = *(const f32x4*)(xb + R * HID + ((k16 ^ sw) << 2));
        f32x4 xc = *(const f32x4*)(xb + R * HID + (((k16 + 1) ^ sw) << 2));
        short8v a;
        a[0] = (short)f2bf(xa[0]); a[1] = (short)f2bf(xa[1]);
        a[2] = (short)f2bf(xa[2]); a[3] = (short)f2bf(xa[3]);
        a[4] = (short)f2bf(xc[0]); a[5] = (short)f2bf(xc[1]);
        a[6] = (short)f2bf(xc[2]); a[7] = (short)f2bf(xc[3]);
        if (rg == 0){
          acc00 = __builtin_amdgcn_mfma_f32_16x16x32_bf16(a, wf0[ks], acc00, 0, 0, 0);
          acc01 = __builtin_amdgcn_mfma_f32_16x16x32_bf16(a, wf1[ks], acc01, 0, 0, 0);
        } else {
          acc10 = __builtin_amdgcn_mfma_f32_16x16x32_bf16(a, wf0[ks], acc10, 0, 0, 0);
          acc11 = __builtin_amdgcn_mfma_f32_16x16x32_bf16(a, wf1[ks], acc11, 0, 0, 0);
        }
      }
    }
    // epilogue: partial score over this wave's 32 hidden dims
    #pragma unroll
    for (int rg = 0; rg < 2; ++rg){
      #pragma unroll
      for (int r = 0; r < 4; ++r){
        float a0 = (rg == 0) ? acc00[r] : acc10[r];
        float a1 = (rg == 0) ? acc01[r] : acc11[r];
        float p = fast_tanh(a0 + b1v0) * w2v0 + fast_tanh(a1 + b1v1) * w2v1;
        p += __shfl_xor(p, 1); p += __shfl_xor(p, 2);
        p += __shfl_xor(p, 4); p += __shfl_xor(p, 8);
        if (col == r) partial_s[wave][rg * 16 + q * 4 + r] = p;
      }
    }
    __syncthreads();   // B1: partials visible

    // ---- e phase (wave 0, lanes 0..31): e = exp(score), denom atomics
    if (tid < TILE){
      float pt = partial_s[0][tid] + partial_s[1][tid]
               + partial_s[2][tid] + partial_s[3][tid];
      float e = __expf(pt + b2v);   // |score| <= sum|w2|+|b2| ~ 6 -> safe, ratios exact
      e_s[tid] = e;
      int b  = b_all[t * TILE + tid];
      int b0 = b_all[t * TILE];
      int bl = b_all[t * TILE + TILE - 1];
      if (b0 == bl){
        float s = e;
        s += __shfl_xor(s, 1);  s += __shfl_xor(s, 2);
        s += __shfl_xor(s, 4);  s += __shfl_xor(s, 8);
        s += __shfl_xor(s, 16);
        if (tid == 0) atomicAdd(&denom[b0], s);
      } else {
        atomicAdd(&denom[b], e);
      }
    }
    __syncthreads();   // B2: e_s visible

    // ---- pool phase: thread owns column c = tid; unnormalized accumulate
    {
      const int chi = tid >> 2, clo = tid & 3;
      #pragma unroll 8
      for (int i = 0; i < TILE; ++i){
        int b   = b_all[t * TILE + i];       // uniform -> no divergence
        float e = e_s[i];
        float xv = xb[i * HID + ((chi ^ (i & 15)) << 2) + clo];
        if (b != curg){
          atomicAdd(&out[(size_t)curg * HID + tid], accp);
          accp = 0.f;
          curg = b;
        }
        accp += e * xv;
      }
    }
  }
  atomicAdd(&out[(size_t)curg * HID + tid], accp);
}

// --- normalize: out[b][c] /= denom[b]
__global__ void k_norm(float* __restrict__ out, const float* __restrict__ denom){
  int g = blockIdx.x, c = threadIdx.x;
  float d = denom[g];
  size_t idx = (size_t)g * HID + c;
  float o = out[idx];
  out[idx] = (d > 0.f) ? __fdividef(o, d) : 0.f;
}

extern "C" void kernel_launch(void* const* d_in, const int* in_sizes, int n_in,
                              void* d_out, int out_size, void* d_ws, size_t ws_size,
                              hipStream_t stream){
  const float* x     = (const float*)d_in[0];
  const int*   batch = (const int*)d_in[1];
  const float* w1    = (const float*)d_in[2];
  const float* b1    = (const float*)d_in[3];
  const float* w2    = (const float*)d_in[4];
  const float* b2    = (const float*)d_in[5];
  float* out = (float*)d_out;

  char* ws = (char*)d_ws;
  unsigned short* w1f = (unsigned short*)ws;     // 65536 B
  float* denom = (float*)(ws + 65536);           // 4096 B

  hipMemsetAsync(denom, 0, 4096, stream);
  hipMemsetAsync(d_out, 0, (size_t)out_size * sizeof(float), stream);

  k_prep<<<16, 256, 0, stream>>>(w1, w1f);
  k_fused<<<NBLOCKS, 256, 0, stream>>>(x, w1f, b1, w2, b2, batch, denom, out);
  k_norm<<<NG, 256, 0, stream>>>(out, denom);
}

// Round 2
// 1474.891 us; speedup vs baseline: 1.2113x; 1.0069x over previous
//
#include <hip/hip_runtime.h>
#include <stdint.h>

#define N_NODES 1000000
#define HID 256
#define HH  128
#define NG  1024
#define TILE 32
#define CHUNK 1984                      // 62 tiles of 32 nodes
#define NBLOCKS ((N_NODES + CHUNK - 1) / CHUNK)   // 505 (last block: 64 nodes)

typedef short short8v __attribute__((ext_vector_type(8)));
typedef float f32x4 __attribute__((ext_vector_type(4)));

#define GLOBAL_AS __attribute__((address_space(1)))
#define LDS_AS    __attribute__((address_space(3)))

// f32 -> bf16 (RNE), inputs finite
__device__ __forceinline__ unsigned short f2bf(float f){
  unsigned u = __float_as_uint(f);
  u += 0x7FFFu + ((u >> 16) & 1u);
  return (unsigned short)(u >> 16);
}

__device__ __forceinline__ float fast_tanh(float v){
  float e = __expf(2.f * v);
  return 1.f - 2.f / (e + 1.f);
}

// --- transform w1 [256][128] f32 -> bf16 B-fragment layout in ws ---
// layout: [nt(8)][ks(8)][lane(64)][i(8)]  where B[k][n]: n = nt*16 + (lane&15),
// k = ks*32 + (lane>>4)*8 + i
__global__ void k_prep(const float* __restrict__ w1, unsigned short* __restrict__ w1f){
  int s = blockIdx.x * blockDim.x + threadIdx.x;
  if (s >= 4096) return;
  int nt = s >> 9, rem = s & 511, ks = rem >> 6, lane = rem & 63;
  int q = lane >> 4, c = lane & 15;
  union { unsigned short u[8]; uint4 v; } tmp;
  for (int i = 0; i < 8; ++i){
    int k = ks * 32 + q * 8 + i;
    int n = nt * 16 + c;
    tmp.u[i] = f2bf(w1[k * HH + n]);
  }
  *(uint4*)(w1f + (size_t)s * 8) = tmp.v;
}

// stage HALF of one 32-node x-tile into LDS via global_load_lds (width 16).
// Each wave owns rows wave*8 .. wave*8+7; half 0 = rr 0..3, half 1 = rr 4..7.
// LDS layout is linear; swizzle (16B-chunk index ^ (row&15)) is applied by
// permuting the per-lane GLOBAL source address (both-sides-or-neither rule).
__device__ __forceinline__ void stage_half(const float* __restrict__ x, long node0,
                                           float* lds_tile, int wave, int lane, int half){
  #pragma unroll
  for (int rr = half * 4; rr < half * 4 + 4; ++rr){
    int r = wave * 8 + rr;
    const float* gp = x + (size_t)(node0 + r) * HID + ((lane ^ (r & 15)) << 2);
    __builtin_amdgcn_global_load_lds(
        (const GLOBAL_AS unsigned int*)gp,
        (LDS_AS unsigned int*)(lds_tile + r * HID),
        16, 0, 0);
  }
}

// --- fused: score (MFMA) + exp + denom atomics + unnormalized pooling.
// Each block owns a contiguous CHUNK of nodes; x is read from HBM exactly once.
// Stage of tile t+1 is issued in two halves (before score, before pool) so the
// vmcnt(0) drain at each __syncthreads never leaves memory idle for long.
__global__ __launch_bounds__(256, 2) void k_fused(
    const float* __restrict__ x, const unsigned short* __restrict__ w1f,
    const float* __restrict__ b1, const float* __restrict__ w2,
    const float* __restrict__ b2, const int* __restrict__ batch,
    float* __restrict__ denom, float* __restrict__ out)
{
  __shared__ __align__(16) float xs[2][TILE * HID];   // 2 x 32 KB double buffer
  __shared__ int   b_all[CHUNK];                      // 7936 B
  __shared__ float partial_s[4][TILE];                // cross-wave score partials

  const int tid = threadIdx.x;
  const long base = (long)blockIdx.x * CHUNK;
  if (base >= N_NODES) return;
  long rem = (long)N_NODES - base;
  const int nvalid = (rem < CHUNK) ? (int)rem : CHUNK;   // always a multiple of 32
  const int ntiles = nvalid / TILE;

  const int wave = tid >> 6, lane = tid & 63;
  const int q = lane >> 4, col = lane & 15;

  // batch chunk -> LDS (synced by the first loop-top barrier)
  for (int i = tid; i < nvalid; i += 256) b_all[i] = batch[base + i];

  // this wave's 2 nt values of w1, kept in registers (64 VGPRs)
  short8v wf0[8], wf1[8];
  #pragma unroll
  for (int ks = 0; ks < 8; ++ks){
    int nt0 = wave * 2;
    wf0[ks] = *(const short8v*)(w1f + (((size_t)nt0 * 8 + ks) * 64 + lane) * 8);
    wf1[ks] = *(const short8v*)(w1f + ((((size_t)nt0 + 1) * 8 + ks) * 64 + lane) * 8);
  }
  float b1v0 = b1[wave * 32 + col],      w2v0 = w2[wave * 32 + col];
  float b1v1 = b1[wave * 32 + 16 + col], w2v1 = w2[wave * 32 + 16 + col];
  const float b2v = b2[0];

  // prologue: stage tile 0 fully
  stage_half(x, base, &xs[0][0], wave, lane, 0);
  stage_half(x, base, &xs[0][0], wave, lane, 1);

  float accp = 0.f;          // pooling accumulator: thread owns column tid
  int curg = batch[base];    // uniform across block

  for (int t = 0; t < ntiles; ++t){
    const int par = t & 1;
    __syncthreads();   // B0: drains stage(t) second half; syncs pool(t-1)/b_all

    // first half of stage(t+1): flies during the score phase
    if (t + 1 < ntiles)
      stage_half(x, base + (long)(t + 1) * TILE, &xs[par ^ 1][0], wave, lane, 0);

    const float* xb = &xs[par][0];

    // ---- score phase: 2 row-groups x 8 k-steps x 2 nt per wave
    f32x4 acc00 = {0.f,0.f,0.f,0.f}, acc01 = {0.f,0.f,0.f,0.f};
    f32x4 acc10 = {0.f,0.f,0.f,0.f}, acc11 = {0.f,0.f,0.f,0.f};
    #pragma unroll
    for (int ks = 0; ks < 8; ++ks){
      const int k16 = ks * 8 + q * 2;
      #pragma unroll
      for (int rg = 0; rg < 2; ++rg){
        const int R  = rg * 16 + col;
        const int sw = R & 15;
        f32x4 xa = *(const f32x4*)(xb + R * HID + ((k16 ^ sw) << 2));
        f32x4 xc = *(const f32x4*)(xb + R * HID + (((k16 + 1) ^ sw) << 2));
        short8v a;
        a[0] = (short)f2bf(xa[0]); a[1] = (short)f2bf(xa[1]);
        a[2] = (short)f2bf(xa[2]); a[3] = (short)f2bf(xa[3]);
        a[4] = (short)f2bf(xc[0]); a[5] = (short)f2bf(xc[1]);
        a[6] = (short)f2bf(xc[2]); a[7] = (short)f2bf(xc[3]);
        if (rg == 0){
          acc00 = __builtin_amdgcn_mfma_f32_16x16x32_bf16(a, wf0[ks], acc00, 0, 0, 0);
          acc01 = __builtin_amdgcn_mfma_f32_16x16x32_bf16(a, wf1[ks], acc01, 0, 0, 0);
        } else {
          acc10 = __builtin_amdgcn_mfma_f32_16x16x32_bf16(a, wf0[ks], acc10, 0, 0, 0);
          acc11 = __builtin_amdgcn_mfma_f32_16x16x32_bf16(a, wf1[ks], acc11, 0, 0, 0);
        }
      }
    }
    // epilogue: partial score over this wave's 32 hidden dims
    #pragma unroll
    for (int rg = 0; rg < 2; ++rg){
      #pragma unroll
      for (int r = 0; r < 4; ++r){
        float a0 = (rg == 0) ? acc00[r] : acc10[r];
        float a1 = (rg == 0) ? acc01[r] : acc11[r];
        float p = fast_tanh(a0 + b1v0) * w2v0 + fast_tanh(a1 + b1v1) * w2v1;
        p += __shfl_xor(p, 1); p += __shfl_xor(p, 2);
        p += __shfl_xor(p, 4); p += __shfl_xor(p, 8);
        if (col == r) partial_s[wave][rg * 16 + q * 4 + r] = p;
      }
    }
    __syncthreads();   // B1: partials visible (also drains stage half 0 - harmless)

    // ---- e phase: every wave computes e for all 32 nodes (lanes l and l+32
    // duplicate; partial_s reads are 2-way broadcast = free). No extra barrier.
    float e_reg;
    {
      const int l32 = lane & 31;
      float pt = partial_s[0][l32] + partial_s[1][l32]
               + partial_s[2][l32] + partial_s[3][l32];
      // |score| <= sum|w2| + |b2| ~ 6 -> exp safe in f32, ratios exact vs ref
      e_reg = __expf(pt + b2v);
    }
    if (wave == 0){
      const int i0 = t * TILE;
      int b0 = b_all[i0];
      int bl = b_all[i0 + TILE - 1];
      if (b0 == bl){
        float s = e_reg;   // lanes 32..63 hold duplicates; reduce masks stay <32
        s += __shfl_xor(s, 1);  s += __shfl_xor(s, 2);
        s += __shfl_xor(s, 4);  s += __shfl_xor(s, 8);
        s += __shfl_xor(s, 16);
        if (lane == 0) atomicAdd(&denom[b0], s);
      } else if (lane < TILE){
        atomicAdd(&denom[b_all[i0 + lane]], e_reg);
      }
    }

    // second half of stage(t+1): flies during the pool phase, drains at next B0
    if (t + 1 < ntiles)
      stage_half(x, base + (long)(t + 1) * TILE, &xs[par ^ 1][0], wave, lane, 1);

    // ---- pool phase: thread owns column c = tid; unnormalized accumulate
    {
      const int chi = tid >> 2, clo = tid & 3;
      #pragma unroll
      for (int i = 0; i < TILE; ++i){
        int b   = b_all[t * TILE + i];       // uniform -> no divergence
        float e = __shfl(e_reg, i);          // constant-lane readlane broadcast
        float xv = xb[i * HID + ((chi ^ (i & 15)) << 2) + clo];
        if (b != curg){
          atomicAdd(&out[(size_t)curg * HID + tid], accp);
          accp = 0.f;
          curg = b;
        }
        accp += e * xv;
      }
    }
  }
  atomicAdd(&out[(size_t)curg * HID + tid], accp);
}

// --- normalize: out[b][c] /= denom[b]
__global__ void k_norm(float* __restrict__ out, const float* __restrict__ denom){
  int g = blockIdx.x, c = threadIdx.x;
  float d = denom[g];
  size_t idx = (size_t)g * HID + c;
  float o = out[idx];
  out[idx] = (d > 0.f) ? __fdividef(o, d) : 0.f;
}

extern "C" void kernel_launch(void* const* d_in, const int* in_sizes, int n_in,
                              void* d_out, int out_size, void* d_ws, size_t ws_size,
                              hipStream_t stream){
  const float* x     = (const float*)d_in[0];
  const int*   batch = (const int*)d_in[1];
  const float* w1    = (const float*)d_in[2];
  const float* b1    = (const float*)d_in[3];
  const float* w2    = (const float*)d_in[4];
  const float* b2    = (const float*)d_in[5];
  float* out = (float*)d_out;

  char* ws = (char*)d_ws;
  unsigned short* w1f = (unsigned short*)ws;     // 65536 B
  float* denom = (float*)(ws + 65536);           // 4096 B

  hipMemsetAsync(denom, 0, 4096, stream);
  hipMemsetAsync(d_out, 0, (size_t)out_size * sizeof(float), stream);

  k_prep<<<16, 256, 0, stream>>>(w1, w1f);
  k_fused<<<NBLOCKS, 256, 0, stream>>>(x, w1f, b1, w2, b2, batch, denom, out);
  k_norm<<<NG, 256, 0, stream>>>(out, denom);
}